// Round 5
// baseline (1904.844 us; speedup 1.0000x reference)
//
#include <hip/hip_runtime.h>
#include <cstdint>
#include <cstddef>

// Problem constants (fixed by reference)
#define NB 2048   // batch
#define ND 256    // D
#define NS 64     // slots
#define NK 1024   // codebook size
#define NREC 5
#define BETA 0.25f

// ---------------- cross-lane helpers ----------------
// DPP row_ror:N moves lane -> (lane+N)%16 within each 16-lane row. Pure VALU.
// CTRL must be a compile-time constant (builtin requirement) -> template param.
template<int CTRL>
__device__ __forceinline__ float dpp_mv(float x){
  union { float f; int i; } u; u.f = x;
  u.i = __builtin_amdgcn_update_dpp(0, u.i, CTRL, 0xF, 0xF, true);
  return u.f;
}
// sum across each 16-lane group, result in ALL lanes of the group (VALU only)
__device__ __forceinline__ float gred_sum16(float v){
  v += dpp_mv<0x128>(v);  // row_ror:8
  v += dpp_mv<0x124>(v);  // row_ror:4
  v += dpp_mv<0x122>(v);  // row_ror:2
  v += dpp_mv<0x121>(v);  // row_ror:1
  return v;
}
__device__ __forceinline__ float gred_max16(float v){
  v = fmaxf(v, dpp_mv<0x128>(v));
  v = fmaxf(v, dpp_mv<0x124>(v));
  v = fmaxf(v, dpp_mv<0x122>(v));
  v = fmaxf(v, dpp_mv<0x121>(v));
  return v;
}
// full-wave reductions: DPP within 16, then xor16 + xor32 shuffles (2 DS ops)
__device__ __forceinline__ float wred_sum64(float v){
  v = gred_sum16(v);
  v += __shfl_xor(v, 16, 64);
  v += __shfl_xor(v, 32, 64);
  return v;
}
__device__ __forceinline__ float wred_max64(float v){
  v = gred_max16(v);
  v = fmaxf(v, __shfl_xor(v, 16, 64));
  v = fmaxf(v, __shfl_xor(v, 32, 64));
  return v;
}

// ---------------- K0: codebook row norms ----------------
__global__ __launch_bounds__(64) void k_ysq(const float* __restrict__ cb,
                                            float* __restrict__ ysq){
  const int cidx = blockIdx.x;
  const int lanev = threadIdx.x;
  const float4* p = reinterpret_cast<const float4*>(cb + (size_t)cidx * (2*ND) + lanev*8);
  float4 a = p[0], b = p[1];
  float sv = a.x*a.x + a.y*a.y + a.z*a.z + a.w*a.w
           + b.x*b.x + b.y*b.y + b.z*b.z + b.w*b.w;
  sv = wred_sum64(sv);
  if (lanev == 0) ysq[cidx] = sv;
}

// ---------------- K1: fused assoc-mem step -----------------------------------
// ROUND-5 RESTRUCTURE: 256-thread block (4 waves) per sample, slots in 4 passes
// of 16 (slot = p*16 + t>>4, chunk c = t&15). Rationale: 1024-thread blocks hit
// the 32-waves/CU cap at 2 blocks/CU -> HBM duty cycle ~25% (all pipes <25%
// busy, occupancy 40%). 4-wave blocks allow 6-8 blocks/CU so different blocks'
// load/compute/store phases overlap.
//  - pass-1: stream mem once, compute sim AND addr-logits (mem not retained).
//  - softmax: wave0 attn || wave1 ww+top3+eff || waves2-3 zero partial buffer.
//  - pass-2: re-read mem (L3-resident), read-partials (xor16/32 + LDS rmw into
//    4 rows) + update+LN+store in the same pass (loads/stores interleaved).
//  - cLN: mean & var in ONE reduction pass (sum, sumsq; ddof=1 via N*mean^2).
//  - __launch_bounds__(256,6): VGPR cap 84 (code fit in 64 before; if <=64 the
//    HW can run 8 blocks/CU). LDS 12.3KB/block - not limiting.
__global__ __launch_bounds__(256, 6) void k_assoc(
    const float* __restrict__ g_r, const float* __restrict__ g_i,
    const float* mem_r_src, const float* mem_i_src,   // may alias dst (in-place)
    float* mem_r_dst, float* mem_i_dst,
    const float* __restrict__ gate_w, const float* __restrict__ gate_b,
    const float* __restrict__ addr_w, const float* __restrict__ addr_b,
    const float* __restrict__ lnr_w, const float* __restrict__ lnr_b,
    const float* __restrict__ lni_w, const float* __restrict__ lni_b,
    const float* __restrict__ cln_s, const float* __restrict__ cln_sh,
    float* __restrict__ zf, float* __restrict__ acc, const int write_mem)
{
  const int t = threadIdx.x;        // 0..255
  const int b = blockIdx.x;
  const int lane = t & 63;
  const int w = t >> 6;             // wave 0..3
  const int sg = t >> 4;            // slot subindex within a pass, 0..15
  const int c = t & 15;             // chunk 0..15
  const int d0 = c << 4;

  __shared__ float s_gr[320], s_gi[320];     // stride 20: dim d at (d>>4)*20+(d&15)
  __shared__ float s_attn[NS], s_ww[NS], s_eff[NS];
  __shared__ float s_gpart[4], s_pq[8];
  __shared__ float s_redA[4*288], s_redB[4*288];  // 4 partial rows, stride 18/chunk

  // ---- g -> LDS + gate partial ----
  {
    float gr = g_r[(size_t)b*ND + t];
    float gi = g_i[(size_t)b*ND + t];
    s_gr[(t>>4)*20 + c] = gr;
    s_gi[(t>>4)*20 + c] = gi;
    if (t < NS) s_eff[t] = 0.f;
    float gp = gr*gate_w[t] + gi*gate_w[ND + t];
    gp = wred_sum64(gp);
    if (lane == 0) s_gpart[w] = gp;
  }
  __syncthreads();                              // A

  // ---- this thread's g chunk -> regs (32 VGPR, reused in all passes) ----
  float gr_[16], gi_[16];
  {
    const float4* p4r = reinterpret_cast<const float4*>(&s_gr[c*20]);
    const float4* p4i = reinterpret_cast<const float4*>(&s_gi[c*20]);
#pragma unroll
    for (int q = 0; q < 4; q++){
      float4 a4 = p4r[q], b4 = p4i[q];
      gr_[4*q+0]=a4.x; gr_[4*q+1]=a4.y; gr_[4*q+2]=a4.z; gr_[4*q+3]=a4.w;
      gi_[4*q+0]=b4.x; gi_[4*q+1]=b4.y; gi_[4*q+2]=b4.z; gi_[4*q+3]=b4.w;
    }
  }

  // ---- pass 1: sim[sl] and addr logits[sl], 4 passes x 16 slots ----
#pragma unroll 1
  for (int p = 0; p < 4; p++){
    const int sl = (p << 4) + sg;
    const size_t mbase = ((size_t)b*NS + sl)*ND + d0;
    const float4* pr  = reinterpret_cast<const float4*>(mem_r_src + mbase);
    const float4* pi  = reinterpret_cast<const float4*>(mem_i_src + mbase);
    const float4* ar4 = reinterpret_cast<const float4*>(addr_w + (size_t)sl*(2*ND) + d0);
    const float4* ai4 = reinterpret_cast<const float4*>(addr_w + (size_t)sl*(2*ND) + ND + d0);
    float sp = 0.f, lp = 0.f;
#pragma unroll
    for (int q = 0; q < 4; q++){
      float4 vr = pr[q], vi = pi[q], ar = ar4[q], ai = ai4[q];
      sp += vr.x*gr_[4*q+0] + vr.y*gr_[4*q+1] + vr.z*gr_[4*q+2] + vr.w*gr_[4*q+3];
      sp += vi.x*gi_[4*q+0] + vi.y*gi_[4*q+1] + vi.z*gi_[4*q+2] + vi.w*gi_[4*q+3];
      lp += ar.x*gr_[4*q+0] + ar.y*gr_[4*q+1] + ar.z*gr_[4*q+2] + ar.w*gr_[4*q+3];
      lp += ai.x*gi_[4*q+0] + ai.y*gi_[4*q+1] + ai.z*gi_[4*q+2] + ai.w*gi_[4*q+3];
    }
    sp = gred_sum16(sp);
    lp = gred_sum16(lp);
    if (c == 0){ s_attn[sl] = sp; s_ww[sl] = lp + addr_b[sl]; }
  }
  __syncthreads();                              // B

  // ---- wave0: attn softmax || wave1: ww softmax+top3+eff || w2-3: zero red ----
  if (w == 0){
    float v = s_attn[lane];
    float mx = wred_max64(v);
    float p = expf(v - mx);
    float sum = wred_sum64(p);
    s_attn[lane] = p / sum;
  } else if (w == 1){
    float lv = s_ww[lane];
    float lmx = wred_max64(lv);
    float lp = expf(lv - lmx);
    float lsum = wred_sum64(lp);
    float wwv = lp / lsum;
    float es = wred_sum64(-wwv * logf(wwv + 1e-10f));
    if (lane == 0) atomicAdd(&acc[0], es * (1.f/NB));   // slot entropy, mean over B
    // top-3 (value desc, tie -> lower index, matching jax top_k)
    float v2 = wwv; const int id0 = lane;
    float tv0=0, tv1=0, tv2=0; int ti0=0, ti1=0, ti2=0;
#pragma unroll
    for (int kk = 0; kk < 3; kk++){
      float bv = v2; int bi = id0;
#pragma unroll
      for (int m = 1; m < 64; m <<= 1){
        float ov = __shfl_xor(bv, m, 64); int oi = __shfl_xor(bi, m, 64);
        if (ov > bv || (ov == bv && oi < bi)){ bv = ov; bi = oi; }
      }
      if (kk == 0){ tv0 = bv; ti0 = bi; }
      else if (kk == 1){ tv1 = bv; ti1 = bi; }
      else { tv2 = bv; ti2 = bi; }
      if (id0 == bi) v2 = -1.f;
    }
    if (lane == 0){
      float wg = 1.f/(1.f + expf(-(s_gpart[0]+s_gpart[1]+s_gpart[2]+s_gpart[3] + gate_b[0])));
      float ssum = tv0 + tv1 + tv2 + 1e-6f;
      s_eff[ti0] = wg * (tv0/ssum);
      s_eff[ti1] = wg * (tv1/ssum);
      s_eff[ti2] = wg * (tv2/ssum);
    }
  } else {
    // waves 2,3: zero the read-partial accumulators
    for (int i = t & 127; i < 4*288; i += 128){ s_redA[i] = 0.f; s_redB[i] = 0.f; }
  }
  __syncthreads();                              // C

  // ---- pass 2: re-read mem; read partials + update+LN+store, interleaved ----
#pragma unroll 1
  for (int p = 0; p < 4; p++){
    const int sl = (p << 4) + sg;
    const size_t mbase = ((size_t)b*NS + sl)*ND + d0;
    float mr[16], mi[16];
    {
      const float4* pr = reinterpret_cast<const float4*>(mem_r_src + mbase);
      const float4* pi = reinterpret_cast<const float4*>(mem_i_src + mbase);
#pragma unroll
      for (int q = 0; q < 4; q++){
        float4 vr = pr[q], vi = pi[q];
        mr[4*q+0]=vr.x; mr[4*q+1]=vr.y; mr[4*q+2]=vr.z; mr[4*q+3]=vr.w;
        mi[4*q+0]=vi.x; mi[4*q+1]=vi.y; mi[4*q+2]=vi.z; mi[4*q+3]=vi.w;
      }
    }
    const float a_w = s_attn[sl];

    // read partials: reduce over this wave's 4 slots (xor16+xor32), accumulate
    // into row w. Same lane RMWs the same address each pass -> no race.
#pragma unroll
    for (int j = 0; j < 16; j += 2){
      float y0 = a_w*mr[j], y1 = a_w*mr[j+1];
      y0 += __shfl_xor(y0, 16, 64); y0 += __shfl_xor(y0, 32, 64);
      y1 += __shfl_xor(y1, 16, 64); y1 += __shfl_xor(y1, 32, 64);
      float z0 = a_w*mi[j], z1 = a_w*mi[j+1];
      z0 += __shfl_xor(z0, 16, 64); z0 += __shfl_xor(z0, 32, 64);
      z1 += __shfl_xor(z1, 16, 64); z1 += __shfl_xor(z1, 32, 64);
      if (lane < 16){
        float2* pa = reinterpret_cast<float2*>(&s_redA[w*288 + lane*18 + j]);
        float2* pb = reinterpret_cast<float2*>(&s_redB[w*288 + lane*18 + j]);
        float2 oa = *pa, ob = *pb;
        *pa = make_float2(oa.x + y0, oa.y + y1);
        *pb = make_float2(ob.x + z0, ob.y + z1);
      }
    }

    // memory update + per-slot LayerNorm + store (dead on final iteration)
    if (write_mem){
      const float effv = s_eff[sl];
      const float onem = 1.f - effv;
      // real
      {
        float ps = 0.f;
#pragma unroll
        for (int j = 0; j < 16; j++){ mr[j] = onem*mr[j] + effv*gr_[j]; ps += mr[j]; }
        float mu = gred_sum16(ps) * (1.f/ND);
        float vs = 0.f;
#pragma unroll
        for (int j = 0; j < 16; j++){ float d_ = mr[j]-mu; vs += d_*d_; }
        float var = gred_sum16(vs) * (1.f/ND);
        float inv = 1.f / sqrtf(var + 1e-6f);
        const float4* lw4 = reinterpret_cast<const float4*>(lnr_w + d0);
        const float4* lb4 = reinterpret_cast<const float4*>(lnr_b + d0);
        float4* pd = reinterpret_cast<float4*>(mem_r_dst + mbase);
#pragma unroll
        for (int q = 0; q < 4; q++){
          float4 wv = lw4[q], bv = lb4[q];
          pd[q] = make_float4((mr[4*q+0]-mu)*inv*wv.x + bv.x,
                              (mr[4*q+1]-mu)*inv*wv.y + bv.y,
                              (mr[4*q+2]-mu)*inv*wv.z + bv.z,
                              (mr[4*q+3]-mu)*inv*wv.w + bv.w);
        }
      }
      // imag
      {
        float ps = 0.f;
#pragma unroll
        for (int j = 0; j < 16; j++){ mi[j] = onem*mi[j] + effv*gi_[j]; ps += mi[j]; }
        float mu = gred_sum16(ps) * (1.f/ND);
        float vs = 0.f;
#pragma unroll
        for (int j = 0; j < 16; j++){ float d_ = mi[j]-mu; vs += d_*d_; }
        float var = gred_sum16(vs) * (1.f/ND);
        float inv = 1.f / sqrtf(var + 1e-6f);
        const float4* lw4 = reinterpret_cast<const float4*>(lni_w + d0);
        const float4* lb4 = reinterpret_cast<const float4*>(lni_b + d0);
        float4* pd = reinterpret_cast<float4*>(mem_i_dst + mbase);
#pragma unroll
        for (int q = 0; q < 4; q++){
          float4 wv = lw4[q], bv = lb4[q];
          pd[q] = make_float4((mi[4*q+0]-mu)*inv*wv.x + bv.x,
                              (mi[4*q+1]-mu)*inv*wv.y + bv.y,
                              (mi[4*q+2]-mu)*inv*wv.z + bv.z,
                              (mi[4*q+3]-mu)*inv*wv.w + bv.w);
        }
      }
    }
  }
  __syncthreads();                              // D

  // ---- gather read, z = g + read, complex layernorm (fused mean/var) ----
  {
    const int offp = (t >> 4)*18 + c;
    float rr = 0.f, ri = 0.f;
#pragma unroll
    for (int w2 = 0; w2 < 4; w2++){
      rr += s_redA[w2*288 + offp];
      ri += s_redB[w2*288 + offp];
    }
    const int offg = (t >> 4)*20 + c;
    float zr = s_gr[offg] + rr;
    float zi = s_gi[offg] + ri;
    float mag = sqrtf(zr*zr + zi*zi + 1e-8f);
    float s1 = wred_sum64(mag);
    float s2 = wred_sum64(mag*mag);
    if (lane == 0){ s_pq[w] = s1; s_pq[4+w] = s2; }
    __syncthreads();                            // E
    const float meanv = (s_pq[0]+s_pq[1]+s_pq[2]+s_pq[3]) * (1.f/ND);
    const float sumsq = s_pq[4]+s_pq[5]+s_pq[6]+s_pq[7];
    const float varv  = (sumsq - (float)ND*meanv*meanv) * (1.f/(ND-1));  // ddof=1
    float nm = (mag - meanv) / sqrtf(varv + 1e-4f) * cln_s[t] + cln_sh[t];
    float sc = nm / mag;     // cos/sin(atan2) = zr/mag, zi/mag
    zf[(size_t)b*(2*ND) + t]      = sc * zr;
    zf[(size_t)b*(2*ND) + ND + t] = sc * zi;
  }
}

// ---------------- K2: batched VQ distances + per-tile argmin -----------------
// grid: 64 sample-tiles(32) x 4 code-tiles(256); 256 threads; fp32 VALU GEMM.
__global__ __launch_bounds__(256) void k_vq_dist(
    const float* __restrict__ zf, const float* __restrict__ codebook,
    const float* __restrict__ ysq, float* __restrict__ pvals, int* __restrict__ pidx)
{
  const int t = threadIdx.x;
  const int mt = blockIdx.x >> 2, nt = blockIdx.x & 3;
  const int sb = mt*32, cbase = nt*256;
  const int jg = t & 31;   // code group: codes cbase + jg*8 .. +7
  const int ig = t >> 5;   // sample group: samples sb + ig*4 .. +3

  __shared__ float s_a[16*36];    // [k][sample] padded to 36
  __shared__ float s_b[16*260];   // [k][code]  padded to 260

  float accv[4][8];
#pragma unroll
  for (int i = 0; i < 4; i++)
#pragma unroll
    for (int j = 0; j < 8; j++) accv[i][j] = 0.f;

  for (int k0 = 0; k0 < 2*ND; k0 += 16){
#pragma unroll
    for (int p = 0; p < 2; p++){
      int e = t + p*256; int i_ = e >> 4; int k_ = e & 15;
      s_a[k_*36 + i_] = zf[(size_t)(sb+i_)*(2*ND) + k0 + k_];
    }
#pragma unroll
    for (int p = 0; p < 16; p++){
      int e = t + p*256; int c_ = e >> 4; int k_ = e & 15;
      s_b[k_*260 + c_] = codebook[(size_t)(cbase+c_)*(2*ND) + k0 + k_];
    }
    __syncthreads();
#pragma unroll
    for (int k = 0; k < 16; k++){
      float4 a4 = *reinterpret_cast<const float4*>(&s_a[k*36 + ig*4]);
      float4 b0 = *reinterpret_cast<const float4*>(&s_b[k*260 + jg*8]);
      float4 b1 = *reinterpret_cast<const float4*>(&s_b[k*260 + jg*8 + 4]);
      const float av[4] = {a4.x, a4.y, a4.z, a4.w};
      const float bv[8] = {b0.x,b0.y,b0.z,b0.w,b1.x,b1.y,b1.z,b1.w};
#pragma unroll
      for (int i = 0; i < 4; i++)
#pragma unroll
        for (int j = 0; j < 8; j++) accv[i][j] = fmaf(av[i], bv[j], accv[i][j]);
    }
    __syncthreads();
  }

  // score = ||c||^2 - 2 <zf,c>  (x_sq / clip(.,0) don't affect argmin here)
#pragma unroll
  for (int i = 0; i < 4; i++){
    float bvv = 1e30f; int bii = 0;
#pragma unroll
    for (int j = 0; j < 8; j++){
      int cg = cbase + jg*8 + j;
      float sc = ysq[cg] - 2.f*accv[i][j];
      if (sc < bvv){ bvv = sc; bii = cg; }  // ascending j -> first-min
    }
#pragma unroll
    for (int m = 1; m < 32; m <<= 1){
      float ov = __shfl_xor(bvv, m, 64); int oi = __shfl_xor(bii, m, 64);
      if (ov < bvv || (ov == bvv && oi < bii)){ bvv = ov; bii = oi; }
    }
    if (jg == 0){
      int smp = sb + ig*4 + i;
      pvals[smp*4 + nt] = bvv;
      pidx [smp*4 + nt] = bii;
    }
  }
}

// ---------------- K3: combine argmin, hist, loss, write next g / output ------
__global__ __launch_bounds__(64) void k_vq_pick(
    const float* __restrict__ pvals, const int* __restrict__ pidx,
    const float* __restrict__ codebook, const float* zf,
    float* __restrict__ g_r, float* __restrict__ g_i, float* out,
    const int final_it, int* __restrict__ hist, float* __restrict__ acc)
{
  const int b = blockIdx.x, lanev = threadIdx.x;
  int sidx = 0;
  if (lanev == 0){
    float bv = pvals[b*4]; int bi = pidx[b*4];
#pragma unroll
    for (int nt = 1; nt < 4; nt++){
      float v = pvals[b*4+nt]; int id = pidx[b*4+nt];
      if (v < bv || (v == bv && id < bi)){ bv = v; bi = id; }
    }
    sidx = bi;
    atomicAdd(&hist[sidx], 1);
  }
  sidx = __shfl(sidx, 0, 64);

  const int e0 = lanev*8;
  const float4* cp = reinterpret_cast<const float4*>(codebook + (size_t)sidx*(2*ND) + e0);
  float4 c0 = cp[0], c1 = cp[1];
  const float4* zp = reinterpret_cast<const float4*>(zf + (size_t)b*(2*ND) + e0);
  float4 z0 = zp[0], z1 = zp[1];
  float ds_ = (c0.x-z0.x)*(c0.x-z0.x) + (c0.y-z0.y)*(c0.y-z0.y)
            + (c0.z-z0.z)*(c0.z-z0.z) + (c0.w-z0.w)*(c0.w-z0.w)
            + (c1.x-z1.x)*(c1.x-z1.x) + (c1.y-z1.y)*(c1.y-z1.y)
            + (c1.z-z1.z)*(c1.z-z1.z) + (c1.w-z1.w)*(c1.w-z1.w);
  ds_ = wred_sum64(ds_);
  if (lanev == 0) atomicAdd(&acc[1], BETA * ds_ * (1.f/(2*ND)) * (1.f/NB));

  if (final_it){
    float4* op = reinterpret_cast<float4*>(out + (size_t)b*(2*ND) + e0);
    op[0] = c0; op[1] = c1;
  } else if (e0 < ND){
    float4* gp = reinterpret_cast<float4*>(g_r + (size_t)b*ND + e0);
    gp[0] = c0; gp[1] = c1;
  } else {
    float4* gp = reinterpret_cast<float4*>(g_i + (size_t)b*ND + (e0-ND));
    gp[0] = c0; gp[1] = c1;
  }
}

// ---------------- K4: aux = slot_ent + loss + codebook entropies -------------
__global__ __launch_bounds__(256) void k_final(const int* __restrict__ hist,
                                               const float* __restrict__ acc,
                                               float* __restrict__ out)
{
  __shared__ float red[256];
  const int t = threadIdx.x;
  float e = 0.f;
  for (int it = 0; it < NREC; it++){
    for (int k = t; k < NK; k += 256){
      float p = (float)hist[it*NK + k] * (1.f/NB);
      e += p * logf(p + 1e-10f);
    }
  }
  red[t] = e;
  __syncthreads();
  for (int off = 128; off > 0; off >>= 1){
    if (t < off) red[t] += red[t+off];
    __syncthreads();
  }
  if (t == 0) out[(size_t)NB*2*ND] = acc[0] + acc[1] - red[0] * (1.f/logf((float)NK));
}

// ---------------- host launch ----------------
extern "C" void kernel_launch(void* const* d_in, const int* in_sizes, int n_in,
                              void* d_out, int out_size, void* d_ws, size_t ws_size,
                              hipStream_t stream)
{
  const float* gwr    = (const float*)d_in[0];
  const float* gwi    = (const float*)d_in[1];
  float*       memr_in= (float*)d_in[2];
  float*       memi_in= (float*)d_in[3];
  const float* gate_w = (const float*)d_in[4];
  const float* gate_b = (const float*)d_in[5];
  const float* addr_w = (const float*)d_in[6];
  const float* addr_b = (const float*)d_in[7];
  const float* lnr_w  = (const float*)d_in[8];
  const float* lnr_b  = (const float*)d_in[9];
  const float* lni_w  = (const float*)d_in[10];
  const float* lni_b  = (const float*)d_in[11];
  const float* cln_s  = (const float*)d_in[12];
  const float* cln_sh = (const float*)d_in[13];
  const float* codebook = (const float*)d_in[14];
  float* out = (float*)d_out;
  char* wsb = (char*)d_ws;

  // ws layout (bytes)
  const size_t OFF_ACC = 0;          // 2 floats
  const size_t OFF_HIST = 256;       // 5*1024 ints
  const size_t OFF_YSQ = 20736;      // 1024 floats
  const size_t OFF_PV  = 24832;      // 2048*4 floats
  const size_t OFF_PI  = 57600;      // 2048*4 ints
  const size_t OFF_GR  = 90368;      // 2048*256 floats
  const size_t OFF_GI  = 2187520;
  const size_t OFF_ZF  = 4284672;    // 2048*512 floats
  const size_t OFF_MR  = 8478976;    // 2048*64*256 floats
  const size_t OFF_MI  = 142696704;
  const size_t NEED_BIG = 276914432;
  const size_t NEED_MID = 8478976;
  const size_t NEED_TINY = 90368;

  if (ws_size < NEED_TINY) return;   // cannot run safely

  float* acc   = (float*)(wsb + OFF_ACC);
  int*   hist  = (int*)  (wsb + OFF_HIST);
  float* ysq   = (float*)(wsb + OFF_YSQ);
  float* pvals = (float*)(wsb + OFF_PV);
  int*   pidx  = (int*)  (wsb + OFF_PI);

  const bool big = ws_size >= NEED_BIG;
  const bool mid = ws_size >= NEED_MID;

  // memory state: ws if it fits, else in-place in d_in (harness restores inputs)
  float* memr_buf = big ? (float*)(wsb + OFF_MR) : memr_in;
  float* memi_buf = big ? (float*)(wsb + OFF_MI) : memi_in;
  float* g_rp = mid ? (float*)(wsb + OFF_GR) : (float*)d_in[0];
  float* g_ip = mid ? (float*)(wsb + OFF_GI) : (float*)d_in[1];
  float* zfp  = mid ? (float*)(wsb + OFF_ZF) : out;   // out[0:1048576] as scratch

  (void)hipMemsetAsync(wsb, 0, OFF_HIST + (size_t)NREC*NK*sizeof(int), stream); // acc+hist

  k_ysq<<<dim3(NK), dim3(64), 0, stream>>>(codebook, ysq);

  const float* gsr = gwr; const float* gsi = gwi;
  const float* msr = memr_in; const float* msi = memi_in;
  for (int it = 0; it < NREC; it++){
    const int write_mem = (it == NREC-1) ? 0 : 1;   // final iter's mem is dead
    k_assoc<<<dim3(NB), dim3(256), 0, stream>>>(
        gsr, gsi, msr, msi, memr_buf, memi_buf,
        gate_w, gate_b, addr_w, addr_b,
        lnr_w, lnr_b, lni_w, lni_b, cln_s, cln_sh, zfp, acc, write_mem);
    k_vq_dist<<<dim3(256), dim3(256), 0, stream>>>(zfp, codebook, ysq, pvals, pidx);
    k_vq_pick<<<dim3(NB), dim3(64), 0, stream>>>(
        pvals, pidx, codebook, zfp, g_rp, g_ip, out,
        (it == NREC-1) ? 1 : 0, hist + it*NK, acc);
    gsr = g_rp; gsi = g_ip;
    msr = memr_buf; msi = memi_buf;
  }
  k_final<<<dim3(1), dim3(256), 0, stream>>>(hist, acc, out);
}

// Round 7
// 1480.439 us; speedup vs baseline: 1.2867x; 1.2867x over previous
//
#include <hip/hip_runtime.h>
#include <cstdint>
#include <cstddef>

// Problem constants (fixed by reference)
#define NB 2048   // batch
#define ND 256    // D
#define NS 64     // slots
#define NK 1024   // codebook size
#define NREC 5
#define BETA 0.25f

// ---------------- cross-lane helpers ----------------
// DPP row_ror:N moves lane -> (lane+N)%16 within each 16-lane row. Pure VALU.
// CTRL must be a compile-time constant (builtin requirement) -> template param.
template<int CTRL>
__device__ __forceinline__ float dpp_mv(float x){
  union { float f; int i; } u; u.f = x;
  u.i = __builtin_amdgcn_update_dpp(0, u.i, CTRL, 0xF, 0xF, true);
  return u.f;
}
// sum across each 16-lane group, result in ALL lanes of the group (VALU only)
__device__ __forceinline__ float gred_sum16(float v){
  v += dpp_mv<0x128>(v);  // row_ror:8
  v += dpp_mv<0x124>(v);  // row_ror:4
  v += dpp_mv<0x122>(v);  // row_ror:2
  v += dpp_mv<0x121>(v);  // row_ror:1
  return v;
}
__device__ __forceinline__ float gred_max16(float v){
  v = fmaxf(v, dpp_mv<0x128>(v));
  v = fmaxf(v, dpp_mv<0x124>(v));
  v = fmaxf(v, dpp_mv<0x122>(v));
  v = fmaxf(v, dpp_mv<0x121>(v));
  return v;
}
// full-wave reductions: DPP within 16, then xor16 + xor32 shuffles (2 DS ops)
__device__ __forceinline__ float wred_sum64(float v){
  v = gred_sum16(v);
  v += __shfl_xor(v, 16, 64);
  v += __shfl_xor(v, 32, 64);
  return v;
}
__device__ __forceinline__ float wred_max64(float v){
  v = gred_max16(v);
  v = fmaxf(v, __shfl_xor(v, 16, 64));
  v = fmaxf(v, __shfl_xor(v, 32, 64));
  return v;
}
// static lane^16 exchange within each 32-lane half (ds_swizzle, no crossbar)
__device__ __forceinline__ float swz_xor16(float x){
  union { float f; int i; } u; u.f = x;
  u.i = __builtin_amdgcn_ds_swizzle(u.i, 0x401F);  // and=0x1F, or=0, xor=0x10
  return u.f;
}

// ---------------- K0: codebook row norms ----------------
__global__ __launch_bounds__(64) void k_ysq(const float* __restrict__ cb,
                                            float* __restrict__ ysq){
  const int cidx = blockIdx.x;
  const int lanev = threadIdx.x;
  const float4* p = reinterpret_cast<const float4*>(cb + (size_t)cidx * (2*ND) + lanev*8);
  float4 a = p[0], b = p[1];
  float sv = a.x*a.x + a.y*a.y + a.z*a.z + a.w*a.w
           + b.x*b.x + b.y*b.y + b.z*b.z + b.w*b.w;
  sv = wred_sum64(sv);
  if (lanev == 0) ysq[cidx] = sv;
}

// ---------------- K1: fused assoc-mem step (one block per sample) -------------
// thread t: slot s = t>>4, chunk c = t&15 -> dims [16c,16c+16). mem row chunk in regs.
// ROUND-7 = ROUND-6 resubmitted (infra failure, kernel never ran).
// ROUND-6 = ROUND-4 structure (best known: 247us) with ONE change:
// the single-address atomicAdd(&acc[0]) is replaced by a per-block plain store
// ws_ent[b]. THEORY: 2048 blocks RMW-ing one L2 line at ~200-500cy each is a
// ~100-250us serialized queue, AND every block's barrier-C vmcnt(0) drain waits
// for its atomic ACK through that queue -> the invariant ~250us floor that no
// structural change (barriers/DPP/DS) could move.
__global__ __launch_bounds__(1024) void k_assoc(
    const float* __restrict__ g_r, const float* __restrict__ g_i,
    const float* mem_r_src, const float* mem_i_src,   // may alias dst (in-place)
    float* mem_r_dst, float* mem_i_dst,
    const float* __restrict__ gate_w, const float* __restrict__ gate_b,
    const float* __restrict__ addr_w, const float* __restrict__ addr_b,
    const float* __restrict__ lnr_w, const float* __restrict__ lnr_b,
    const float* __restrict__ lni_w, const float* __restrict__ lni_b,
    const float* __restrict__ cln_s, const float* __restrict__ cln_sh,
    float* __restrict__ zf, float* __restrict__ ent, const int write_mem)
{
  const int t = threadIdx.x;
  const int b = blockIdx.x;
  const int lane = t & 63;
  const int w = t >> 6;       // wave 0..15
  const int s = t >> 4;       // slot 0..63
  const int c = t & 15;       // chunk
  const int d0 = c << 4;

  __shared__ float s_gr[320], s_gi[320];        // stride 20: elem d at (d>>4)*20+(d&15)
  __shared__ float s_attn[NS], s_ww[NS], s_eff[NS];
  __shared__ float s_gpart[4], s_p[4], s_q[4];
  __shared__ float s_redA[32*288];              // 32 partial rows, stride 288=16*18
  __shared__ float s_redB[32*288];

  // ---- issue mem row loads first (HBM latency hides under the g/gate work) --
  float mr[16], mi[16];
  const size_t base = ((size_t)b*NS + s)*ND + d0;
  {
    const float4* pr = reinterpret_cast<const float4*>(mem_r_src + base);
    const float4* pi = reinterpret_cast<const float4*>(mem_i_src + base);
#pragma unroll
    for (int q = 0; q < 4; q++){
      float4 vr = pr[q], vi = pi[q];
      mr[4*q+0]=vr.x; mr[4*q+1]=vr.y; mr[4*q+2]=vr.z; mr[4*q+3]=vr.w;
      mi[4*q+0]=vi.x; mi[4*q+1]=vi.y; mi[4*q+2]=vi.z; mi[4*q+3]=vi.w;
    }
  }

  // ---- g -> LDS (stride 20) + gate partial via wave reduction (waves 0-3) ----
  if (t < ND){
    float gr = g_r[(size_t)b*ND + t];
    float gi = g_i[(size_t)b*ND + t];
    s_gr[(t>>4)*20 + (t&15)] = gr;
    s_gi[(t>>4)*20 + (t&15)] = gi;
    float gp = gr*gate_w[t] + gi*gate_w[ND + t];
    gp = wred_sum64(gp);
    if (lane == 0) s_gpart[w] = gp;
  }
  if (t < NS) s_eff[t] = 0.f;
  __syncthreads();                              // A

  const float4* sgr4 = reinterpret_cast<const float4*>(&s_gr[c*20]);
  const float4* sgi4 = reinterpret_cast<const float4*>(&s_gi[c*20]);

  float gr_[16], gi_[16];                        // this chunk of g, from LDS b128
#pragma unroll
  for (int q = 0; q < 4; q++){
    float4 a4 = sgr4[q], b4 = sgi4[q];
    gr_[4*q+0]=a4.x; gr_[4*q+1]=a4.y; gr_[4*q+2]=a4.z; gr_[4*q+3]=a4.w;
    gi_[4*q+0]=b4.x; gi_[4*q+1]=b4.y; gi_[4*q+2]=b4.z; gi_[4*q+3]=b4.w;
  }

  // ---- sim[s] = <mr, gr> + <mi, gi> (VALU-only reduction) ----
  {
    float sp = 0.f;
#pragma unroll
    for (int j = 0; j < 16; j++) sp += mr[j]*gr_[j] + mi[j]*gi_[j];
    sp = gred_sum16(sp);
    if (c == 0) s_attn[s] = sp;
  }
  // ---- addr logits[s] ----
  {
    const float4* awr = reinterpret_cast<const float4*>(addr_w + (size_t)s*(2*ND) + d0);
    const float4* awi = reinterpret_cast<const float4*>(addr_w + (size_t)s*(2*ND) + ND + d0);
    float lp = 0.f;
#pragma unroll
    for (int q = 0; q < 4; q++){
      float4 ar = awr[q], ai = awi[q];
      lp += gr_[4*q+0]*ar.x + gr_[4*q+1]*ar.y + gr_[4*q+2]*ar.z + gr_[4*q+3]*ar.w;
      lp += gi_[4*q+0]*ai.x + gi_[4*q+1]*ai.y + gi_[4*q+2]*ai.z + gi_[4*q+3]*ai.w;
    }
    lp = gred_sum16(lp);
    if (c == 0) s_ww[s] = lp + addr_b[s];
  }
  __syncthreads();                              // B

  // ---- wave0: attn softmax  ||  wave1: ww softmax + entropy + top3 + eff ----
  if (w == 0){
    float v = s_attn[lane];
    float mx = wred_max64(v);
    float p = expf(v - mx);
    float sum = wred_sum64(p);
    s_attn[lane] = p / sum;
  } else if (w == 1){
    float lv = s_ww[lane];
    float lmx = wred_max64(lv);
    float lp = expf(lv - lmx);
    float lsum = wred_sum64(lp);
    float wwv = lp / lsum;
    float es = wred_sum64(-wwv * logf(wwv + 1e-10f));
    if (lane == 0) ent[b] = es;                 // plain store, no same-address atomic
    // top-3 (value desc, tie -> lower index, matching jax top_k)
    float v2 = wwv; const int id0 = lane;
    float tv0=0, tv1=0, tv2=0; int ti0=0, ti1=0, ti2=0;
#pragma unroll
    for (int kk = 0; kk < 3; kk++){
      float bv = v2; int bi = id0;
#pragma unroll
      for (int m = 1; m < 64; m <<= 1){
        float ov = __shfl_xor(bv, m, 64); int oi = __shfl_xor(bi, m, 64);
        if (ov > bv || (ov == bv && oi < bi)){ bv = ov; bi = oi; }
      }
      if (kk == 0){ tv0 = bv; ti0 = bi; }
      else if (kk == 1){ tv1 = bv; ti1 = bi; }
      else { tv2 = bv; ti2 = bi; }
      if (id0 == bi) v2 = -1.f;
    }
    if (lane == 0){
      float wg = 1.f/(1.f + expf(-(s_gpart[0]+s_gpart[1]+s_gpart[2]+s_gpart[3] + gate_b[0])));
      float ssum = tv0 + tv1 + tv2 + 1e-6f;
      s_eff[ti0] = wg * (tv0/ssum);
      s_eff[ti1] = wg * (tv1/ssum);
      s_eff[ti2] = wg * (tv2/ssum);
    }
  }
  __syncthreads();                              // C

  // ---- attn-weighted read partials: swizzle(xor16) + 2 half-rows per wave ----
  // lanes 0-15 hold slots {4w,4w+1} partial (row 2w); lanes 32-47 hold
  // {4w+2,4w+3} (row 2w+1). float2 writes, 8B aligned (stride 18, even j).
  const float a_w = s_attn[s];
  {
    const bool wr_ok = ((lane & 31) < 16);
    const int row = 2*w + (lane >> 5);
    float* dstA = &s_redA[row*288 + (lane & 15)*18];
    float* dstB = &s_redB[row*288 + (lane & 15)*18];
#pragma unroll
    for (int j = 0; j < 16; j += 2){
      float x0 = a_w * mr[j],   x1 = a_w * mr[j+1];
      float y0 = x0 + swz_xor16(x0);
      float y1 = x1 + swz_xor16(x1);
      if (wr_ok) *reinterpret_cast<float2*>(dstA + j) = make_float2(y0, y1);
    }
#pragma unroll
    for (int j = 0; j < 16; j += 2){
      float x0 = a_w * mi[j],   x1 = a_w * mi[j+1];
      float y0 = x0 + swz_xor16(x0);
      float y1 = x1 + swz_xor16(x1);
      if (wr_ok) *reinterpret_cast<float2*>(dstB + j) = make_float2(y0, y1);
    }
  }

  // ---- mem update + per-slot LayerNorm, IN-PLACE into mr/mi (store later) ----
  if (write_mem){
    const float effv = s_eff[s];
    const float onem = 1.f - effv;
    // real
    {
      float ps = 0.f;
#pragma unroll
      for (int j = 0; j < 16; j++){ mr[j] = onem*mr[j] + effv*gr_[j]; ps += mr[j]; }
      float mu = gred_sum16(ps) * (1.f/ND);
      float vs = 0.f;
#pragma unroll
      for (int j = 0; j < 16; j++){ float d_ = mr[j]-mu; vs += d_*d_; }
      float var = gred_sum16(vs) * (1.f/ND);
      float inv = 1.f / sqrtf(var + 1e-6f);
      const float4* lw4 = reinterpret_cast<const float4*>(lnr_w + d0);
      const float4* lb4 = reinterpret_cast<const float4*>(lnr_b + d0);
#pragma unroll
      for (int q = 0; q < 4; q++){
        float4 wv = lw4[q], bv = lb4[q];
        mr[4*q+0] = (mr[4*q+0]-mu)*inv*wv.x + bv.x;
        mr[4*q+1] = (mr[4*q+1]-mu)*inv*wv.y + bv.y;
        mr[4*q+2] = (mr[4*q+2]-mu)*inv*wv.z + bv.z;
        mr[4*q+3] = (mr[4*q+3]-mu)*inv*wv.w + bv.w;
      }
    }
    // imag
    {
      float ps = 0.f;
#pragma unroll
      for (int j = 0; j < 16; j++){ mi[j] = onem*mi[j] + effv*gi_[j]; ps += mi[j]; }
      float mu = gred_sum16(ps) * (1.f/ND);
      float vs = 0.f;
#pragma unroll
      for (int j = 0; j < 16; j++){ float d_ = mi[j]-mu; vs += d_*d_; }
      float var = gred_sum16(vs) * (1.f/ND);
      float inv = 1.f / sqrtf(var + 1e-6f);
      const float4* lw4 = reinterpret_cast<const float4*>(lni_w + d0);
      const float4* lb4 = reinterpret_cast<const float4*>(lni_b + d0);
#pragma unroll
      for (int q = 0; q < 4; q++){
        float4 wv = lw4[q], bv = lb4[q];
        mi[4*q+0] = (mi[4*q+0]-mu)*inv*wv.x + bv.x;
        mi[4*q+1] = (mi[4*q+1]-mu)*inv*wv.y + bv.y;
        mi[4*q+2] = (mi[4*q+2]-mu)*inv*wv.z + bv.z;
        mi[4*q+3] = (mi[4*q+3]-mu)*inv*wv.w + bv.w;
      }
    }
  }
  __syncthreads();                              // D

  // ---- gather read (32 partial rows), z = g + read, complex layernorm ----
  float zr = 0.f, zi = 0.f, mag = 1.f;
  if (t < ND){
    const int offp = (t >> 4)*18 + (t & 15);
    float rr = 0.f, ri = 0.f;
#pragma unroll
    for (int r2 = 0; r2 < 32; r2++){
      rr += s_redA[r2*288 + offp];
      ri += s_redB[r2*288 + offp];
    }
    const int offg = (t >> 4)*20 + (t & 15);
    zr = s_gr[offg] + rr;
    zi = s_gi[offg] + ri;
    mag = sqrtf(zr*zr + zi*zi + 1e-8f);
    float ps = wred_sum64(mag);
    if (lane == 0) s_p[w] = ps;
  }
  __syncthreads();                              // E
  const float meanv = (s_p[0]+s_p[1]+s_p[2]+s_p[3]) * (1.f/ND);
  if (t < ND){
    float d_ = mag - meanv;
    float qs = wred_sum64(d_*d_);
    if (lane == 0) s_q[w] = qs;
  }
  __syncthreads();                              // F
  if (t < ND){
    const float varv = (s_q[0]+s_q[1]+s_q[2]+s_q[3]) * (1.f/(ND-1));  // ddof=1
    float nm = (mag - meanv) / sqrtf(varv + 1e-4f) * cln_s[t] + cln_sh[t];
    float sc = nm / mag;     // cos/sin(atan2) = zr/mag, zi/mag
    zf[(size_t)b*(2*ND) + t]      = sc * zr;
    zf[(size_t)b*(2*ND) + ND + t] = sc * zi;
  }

  // ---- mem store last: no barrier waits on the vmcnt drain ----
  if (write_mem){
    float4* pdr = reinterpret_cast<float4*>(mem_r_dst + base);
    float4* pdi = reinterpret_cast<float4*>(mem_i_dst + base);
#pragma unroll
    for (int q = 0; q < 4; q++){
      pdr[q] = make_float4(mr[4*q], mr[4*q+1], mr[4*q+2], mr[4*q+3]);
      pdi[q] = make_float4(mi[4*q], mi[4*q+1], mi[4*q+2], mi[4*q+3]);
    }
  }
}

// ---------------- K2: batched VQ distances + per-tile argmin -----------------
// grid: 64 sample-tiles(32) x 4 code-tiles(256); 256 threads; fp32 VALU GEMM.
__global__ __launch_bounds__(256) void k_vq_dist(
    const float* __restrict__ zf, const float* __restrict__ codebook,
    const float* __restrict__ ysq, float* __restrict__ pvals, int* __restrict__ pidx)
{
  const int t = threadIdx.x;
  const int mt = blockIdx.x >> 2, nt = blockIdx.x & 3;
  const int sb = mt*32, cbase = nt*256;
  const int jg = t & 31;   // code group: codes cbase + jg*8 .. +7
  const int ig = t >> 5;   // sample group: samples sb + ig*4 .. +3

  __shared__ float s_a[16*36];    // [k][sample] padded to 36
  __shared__ float s_b[16*260];   // [k][code]  padded to 260

  float accv[4][8];
#pragma unroll
  for (int i = 0; i < 4; i++)
#pragma unroll
    for (int j = 0; j < 8; j++) accv[i][j] = 0.f;

  for (int k0 = 0; k0 < 2*ND; k0 += 16){
#pragma unroll
    for (int p = 0; p < 2; p++){
      int e = t + p*256; int i_ = e >> 4; int k_ = e & 15;
      s_a[k_*36 + i_] = zf[(size_t)(sb+i_)*(2*ND) + k0 + k_];
    }
#pragma unroll
    for (int p = 0; p < 16; p++){
      int e = t + p*256; int c_ = e >> 4; int k_ = e & 15;
      s_b[k_*260 + c_] = codebook[(size_t)(cbase+c_)*(2*ND) + k0 + k_];
    }
    __syncthreads();
#pragma unroll
    for (int k = 0; k < 16; k++){
      float4 a4 = *reinterpret_cast<const float4*>(&s_a[k*36 + ig*4]);
      float4 b0 = *reinterpret_cast<const float4*>(&s_b[k*260 + jg*8]);
      float4 b1 = *reinterpret_cast<const float4*>(&s_b[k*260 + jg*8 + 4]);
      const float av[4] = {a4.x, a4.y, a4.z, a4.w};
      const float bv[8] = {b0.x,b0.y,b0.z,b0.w,b1.x,b1.y,b1.z,b1.w};
#pragma unroll
      for (int i = 0; i < 4; i++)
#pragma unroll
        for (int j = 0; j < 8; j++) accv[i][j] = fmaf(av[i], bv[j], accv[i][j]);
    }
    __syncthreads();
  }

  // score = ||c||^2 - 2 <zf,c>  (x_sq / clip(.,0) don't affect argmin here)
#pragma unroll
  for (int i = 0; i < 4; i++){
    float bvv = 1e30f; int bii = 0;
#pragma unroll
    for (int j = 0; j < 8; j++){
      int cg = cbase + jg*8 + j;
      float sc = ysq[cg] - 2.f*accv[i][j];
      if (sc < bvv){ bvv = sc; bii = cg; }  // ascending j -> first-min
    }
#pragma unroll
    for (int m = 1; m < 32; m <<= 1){
      float ov = __shfl_xor(bvv, m, 64); int oi = __shfl_xor(bii, m, 64);
      if (ov < bvv || (ov == bvv && oi < bii)){ bvv = ov; bii = oi; }
    }
    if (jg == 0){
      int smp = sb + ig*4 + i;
      pvals[smp*4 + nt] = bvv;
      pidx [smp*4 + nt] = bii;
    }
  }
}

// ---------------- K3: combine argmin, hist, loss, write next g / output ------
__global__ __launch_bounds__(64) void k_vq_pick(
    const float* __restrict__ pvals, const int* __restrict__ pidx,
    const float* __restrict__ codebook, const float* zf,
    float* __restrict__ g_r, float* __restrict__ g_i, float* out,
    const int final_it, int* __restrict__ hist, float* __restrict__ dsv)
{
  const int b = blockIdx.x, lanev = threadIdx.x;
  int sidx = 0;
  if (lanev == 0){
    float bv = pvals[b*4]; int bi = pidx[b*4];
#pragma unroll
    for (int nt = 1; nt < 4; nt++){
      float v = pvals[b*4+nt]; int id = pidx[b*4+nt];
      if (v < bv || (v == bv && id < bi)){ bv = v; bi = id; }
    }
    sidx = bi;
    atomicAdd(&hist[sidx], 1);   // scattered over 1024 bins: low contention
  }
  sidx = __shfl(sidx, 0, 64);

  const int e0 = lanev*8;
  const float4* cp = reinterpret_cast<const float4*>(codebook + (size_t)sidx*(2*ND) + e0);
  float4 c0 = cp[0], c1 = cp[1];
  const float4* zp = reinterpret_cast<const float4*>(zf + (size_t)b*(2*ND) + e0);
  float4 z0 = zp[0], z1 = zp[1];
  float ds_ = (c0.x-z0.x)*(c0.x-z0.x) + (c0.y-z0.y)*(c0.y-z0.y)
            + (c0.z-z0.z)*(c0.z-z0.z) + (c0.w-z0.w)*(c0.w-z0.w)
            + (c1.x-z1.x)*(c1.x-z1.x) + (c1.y-z1.y)*(c1.y-z1.y)
            + (c1.z-z1.z)*(c1.z-z1.z) + (c1.w-z1.w)*(c1.w-z1.w);
  ds_ = wred_sum64(ds_);
  if (lanev == 0) dsv[b] = ds_;   // plain store; scaled + summed in k_final

  if (final_it){
    float4* op = reinterpret_cast<float4*>(out + (size_t)b*(2*ND) + e0);
    op[0] = c0; op[1] = c1;
  } else if (e0 < ND){
    float4* gp = reinterpret_cast<float4*>(g_r + (size_t)b*ND + e0);
    gp[0] = c0; gp[1] = c1;
  } else {
    float4* gp = reinterpret_cast<float4*>(g_i + (size_t)b*ND + (e0-ND));
    gp[0] = c0; gp[1] = c1;
  }
}

// ---------------- K4: aux = slot_ent + vq_loss + codebook entropies ----------
__global__ __launch_bounds__(256) void k_final(const int* __restrict__ hist,
                                               const float* __restrict__ ent,
                                               const float* __restrict__ dsv,
                                               float* __restrict__ out)
{
  __shared__ float redh[256], reda[256];
  const int t = threadIdx.x;
  float h = 0.f;
  for (int it = 0; it < NREC; it++){
    for (int k = t; k < NK; k += 256){
      float p = (float)hist[it*NK + k] * (1.f/NB);
      h += p * logf(p + 1e-10f);
    }
  }
  float a = 0.f;
  for (int i = t; i < NREC*NB; i += 256) a += ent[i];
  float d = 0.f;
  for (int i = t; i < NREC*NB; i += 256) d += dsv[i];
  redh[t] = h;
  reda[t] = a * (1.f/NB) + d * (BETA/(2.f*ND*NB));
  __syncthreads();
  for (int off = 128; off > 0; off >>= 1){
    if (t < off){ redh[t] += redh[t+off]; reda[t] += reda[t+off]; }
    __syncthreads();
  }
  if (t == 0) out[(size_t)NB*2*ND] = reda[0] - redh[0] * (1.f/logf((float)NK));
}

// ---------------- host launch ----------------
extern "C" void kernel_launch(void* const* d_in, const int* in_sizes, int n_in,
                              void* d_out, int out_size, void* d_ws, size_t ws_size,
                              hipStream_t stream)
{
  const float* gwr    = (const float*)d_in[0];
  const float* gwi    = (const float*)d_in[1];
  float*       memr_in= (float*)d_in[2];
  float*       memi_in= (float*)d_in[3];
  const float* gate_w = (const float*)d_in[4];
  const float* gate_b = (const float*)d_in[5];
  const float* addr_w = (const float*)d_in[6];
  const float* addr_b = (const float*)d_in[7];
  const float* lnr_w  = (const float*)d_in[8];
  const float* lnr_b  = (const float*)d_in[9];
  const float* lni_w  = (const float*)d_in[10];
  const float* lni_b  = (const float*)d_in[11];
  const float* cln_s  = (const float*)d_in[12];
  const float* cln_sh = (const float*)d_in[13];
  const float* codebook = (const float*)d_in[14];
  float* out = (float*)d_out;
  char* wsb = (char*)d_ws;

  // ws layout (bytes)
  const size_t OFF_HIST = 256;        // 5*1024 ints              -> ends 20736
  const size_t OFF_ENT  = 20736;      // 5*2048 floats            -> ends 61696
  const size_t OFF_DS   = 61696;      // 5*2048 floats            -> ends 102656
  const size_t OFF_YSQ  = 102656;     // 1024 floats              -> ends 106752
  const size_t OFF_PV   = 106752;     // 2048*4 floats            -> ends 139520
  const size_t OFF_PI   = 139520;     // 2048*4 ints              -> ends 172288
  const size_t OFF_GR   = 172288;     // 2048*256 floats          -> ends 2269440
  const size_t OFF_GI   = 2269440;    //                          -> ends 4366592
  const size_t OFF_ZF   = 4366592;    // 2048*512 floats          -> ends 8560896
  const size_t OFF_MR   = 8560896;    // 2048*64*256 floats       -> ends 142778624
  const size_t OFF_MI   = 142778624;  //                          -> ends 276996352
  const size_t NEED_BIG = 276996352;
  const size_t NEED_MID = 8560896;
  const size_t NEED_TINY = 172288;

  if (ws_size < NEED_TINY) return;   // cannot run safely

  int*   hist  = (int*)  (wsb + OFF_HIST);
  float* ws_ent= (float*)(wsb + OFF_ENT);
  float* ws_ds = (float*)(wsb + OFF_DS);
  float* ysq   = (float*)(wsb + OFF_YSQ);
  float* pvals = (float*)(wsb + OFF_PV);
  int*   pidx  = (int*)  (wsb + OFF_PI);

  const bool big = ws_size >= NEED_BIG;
  const bool mid = ws_size >= NEED_MID;

  // memory state: ws if it fits, else in-place in d_in (harness restores inputs)
  float* memr_buf = big ? (float*)(wsb + OFF_MR) : memr_in;
  float* memi_buf = big ? (float*)(wsb + OFF_MI) : memi_in;
  float* g_rp = mid ? (float*)(wsb + OFF_GR) : (float*)d_in[0];
  float* g_ip = mid ? (float*)(wsb + OFF_GI) : (float*)d_in[1];
  float* zfp  = mid ? (float*)(wsb + OFF_ZF) : out;   // out[0:1048576] as scratch

  (void)hipMemsetAsync(wsb, 0, OFF_YSQ, stream);   // hist + ent + ds

  k_ysq<<<dim3(NK), dim3(64), 0, stream>>>(codebook, ysq);

  const float* gsr = gwr; const float* gsi = gwi;
  const float* msr = memr_in; const float* msi = memi_in;
  for (int it = 0; it < NREC; it++){
    const int write_mem = (it == NREC-1) ? 0 : 1;   // final iter's mem is dead
    k_assoc<<<dim3(NB), dim3(1024), 0, stream>>>(
        gsr, gsi, msr, msi, memr_buf, memi_buf,
        gate_w, gate_b, addr_w, addr_b,
        lnr_w, lnr_b, lni_w, lni_b, cln_s, cln_sh, zfp,
        ws_ent + (size_t)it*NB, write_mem);
    k_vq_dist<<<dim3(256), dim3(256), 0, stream>>>(zfp, codebook, ysq, pvals, pidx);
    k_vq_pick<<<dim3(NB), dim3(64), 0, stream>>>(
        pvals, pidx, codebook, zfp, g_rp, g_ip, out,
        (it == NREC-1) ? 1 : 0, hist + it*NK, ws_ds + (size_t)it*NB);
    gsr = g_rp; gsi = g_ip;
    msr = memr_buf; msi = memi_buf;
  }
  k_final<<<dim3(1), dim3(256), 0, stream>>>(hist, ws_ent, ws_ds, out);
}

// Round 9
// 1272.337 us; speedup vs baseline: 1.4971x; 1.1636x over previous
//
#include <hip/hip_runtime.h>
#include <cstdint>
#include <cstddef>

// Problem constants (fixed by reference)
#define NB 2048   // batch
#define ND 256    // D
#define NS 64     // slots
#define NK 1024   // codebook size
#define NREC 5
#define BETA 0.25f

// ---------------- cross-lane helpers ----------------
template<int CTRL>
__device__ __forceinline__ float dpp_mv(float x){
  union { float f; int i; } u; u.f = x;
  u.i = __builtin_amdgcn_update_dpp(0, u.i, CTRL, 0xF, 0xF, true);
  return u.f;
}
// sum across each 16-lane group (VALU only)
__device__ __forceinline__ float gred_sum16(float v){
  v += dpp_mv<0x128>(v);  // row_ror:8
  v += dpp_mv<0x124>(v);  // row_ror:4
  v += dpp_mv<0x122>(v);  // row_ror:2
  v += dpp_mv<0x121>(v);  // row_ror:1
  return v;
}
__device__ __forceinline__ float gred_max16(float v){
  v = fmaxf(v, dpp_mv<0x128>(v));
  v = fmaxf(v, dpp_mv<0x124>(v));
  v = fmaxf(v, dpp_mv<0x122>(v));
  v = fmaxf(v, dpp_mv<0x121>(v));
  return v;
}
__device__ __forceinline__ float wred_sum64(float v){
  v = gred_sum16(v);
  v += __shfl_xor(v, 16, 64);
  v += __shfl_xor(v, 32, 64);
  return v;
}
__device__ __forceinline__ float wred_max64(float v){
  v = gred_max16(v);
  v = fmaxf(v, __shfl_xor(v, 16, 64));
  v = fmaxf(v, __shfl_xor(v, 32, 64));
  return v;
}

// ---------------- K0: codebook row norms ----------------
__global__ __launch_bounds__(64) void k_ysq(const float* __restrict__ cb,
                                            float* __restrict__ ysq){
  const int cidx = blockIdx.x;
  const int lanev = threadIdx.x;
  const float4* p = reinterpret_cast<const float4*>(cb + (size_t)cidx * (2*ND) + lanev*8);
  float4 a = p[0], b = p[1];
  float sv = a.x*a.x + a.y*a.y + a.z*a.z + a.w*a.w
           + b.x*b.x + b.y*b.y + b.z*b.z + b.w*b.w;
  sv = wred_sum64(sv);
  if (lanev == 0) ysq[cidx] = sv;
}

// ---------------- K-eff: ww softmax / top3 / gate -> eff  (NO mem dependence) -
// ROUND-9 = ROUND-8 resubmitted (infra failure; kernel never ran).
// INSIGHT: eff = f(g, addr_w, gate_w) only. Computing it up front lets
// the main kernel do ONE streaming pass over mem with online softmax for attn.
__global__ __launch_bounds__(256) void k_eff(
    const float* __restrict__ g_r, const float* __restrict__ g_i,
    const float* __restrict__ addr_w, const float* __restrict__ addr_b,
    const float* __restrict__ gate_w, const float* __restrict__ gate_b,
    float* __restrict__ effw, float* __restrict__ ent)
{
  const int t = threadIdx.x, b = blockIdx.x;
  const int lane = t & 63, w = t >> 6, sg = t >> 4, c = t & 15, d0 = c << 4;
  __shared__ float s_ww[NS];
  __shared__ float s_wg;

  // this thread's g chunk (dims d0..d0+16)
  float gr_[16], gi_[16];
  {
    const float4* pr = reinterpret_cast<const float4*>(g_r + (size_t)b*ND + d0);
    const float4* pi = reinterpret_cast<const float4*>(g_i + (size_t)b*ND + d0);
#pragma unroll
    for (int q = 0; q < 4; q++){
      float4 a4 = pr[q], b4 = pi[q];
      gr_[4*q+0]=a4.x; gr_[4*q+1]=a4.y; gr_[4*q+2]=a4.z; gr_[4*q+3]=a4.w;
      gi_[4*q+0]=b4.x; gi_[4*q+1]=b4.y; gi_[4*q+2]=b4.z; gi_[4*q+3]=b4.w;
    }
  }
  // addr logits, 4 passes x 16 slots
#pragma unroll 1
  for (int p = 0; p < 4; p++){
    const int sl = (p << 4) + sg;
    const float4* ar4 = reinterpret_cast<const float4*>(addr_w + (size_t)sl*(2*ND) + d0);
    const float4* ai4 = reinterpret_cast<const float4*>(addr_w + (size_t)sl*(2*ND) + ND + d0);
    float lp = 0.f;
#pragma unroll
    for (int q = 0; q < 4; q++){
      float4 ar = ar4[q], ai = ai4[q];
      lp += gr_[4*q+0]*ar.x + gr_[4*q+1]*ar.y + gr_[4*q+2]*ar.z + gr_[4*q+3]*ar.w;
      lp += gi_[4*q+0]*ai.x + gi_[4*q+1]*ai.y + gi_[4*q+2]*ai.z + gi_[4*q+3]*ai.w;
    }
    lp = gred_sum16(lp);
    if (c == 0) s_ww[sl] = lp + addr_b[sl];
  }
  // gate partial: sg==0 threads cover all 16 chunks
  if (sg == 0){
    float gp = 0.f;
#pragma unroll
    for (int j = 0; j < 16; j++)
      gp += gr_[j]*gate_w[d0+j] + gi_[j]*gate_w[ND+d0+j];
    gp = gred_sum16(gp);
    if (t == 0) s_wg = gp;
  }
  __syncthreads();

  if (w == 0){
    float lv = s_ww[lane];
    float lmx = wred_max64(lv);
    float lp2 = expf(lv - lmx);
    float lsum = wred_sum64(lp2);
    float wwv = lp2 / lsum;
    float es = wred_sum64(-wwv * logf(wwv + 1e-10f));
    if (lane == 0) ent[b] = es;
    // top-3 (value desc, tie -> lower index); results wave-uniform
    float v2 = wwv; const int id0 = lane;
    float tv0=0, tv1=0, tv2=0; int ti0=0, ti1=0, ti2=0;
#pragma unroll
    for (int kk = 0; kk < 3; kk++){
      float bv = v2; int bi = id0;
#pragma unroll
      for (int m = 1; m < 64; m <<= 1){
        float ov = __shfl_xor(bv, m, 64); int oi = __shfl_xor(bi, m, 64);
        if (ov > bv || (ov == bv && oi < bi)){ bv = ov; bi = oi; }
      }
      if (kk == 0){ tv0 = bv; ti0 = bi; }
      else if (kk == 1){ tv1 = bv; ti1 = bi; }
      else { tv2 = bv; ti2 = bi; }
      if (id0 == bi) v2 = -1.f;
    }
    float wg = 1.f/(1.f + expf(-(s_wg + gate_b[0])));
    float ssum = tv0 + tv1 + tv2 + 1e-6f;
    float ev = 0.f;
    if      (lane == ti0) ev = wg * (tv0/ssum);
    else if (lane == ti1) ev = wg * (tv1/ssum);
    else if (lane == ti2) ev = wg * (tv2/ssum);
    effw[(size_t)b*NS + lane] = ev;   // every lane writes its slot: no race
  }
}

// ---------------- K-main: ONE streaming pass over mem ------------------------
// 256 threads (sg=t>>4 slot-group, c=t&15 chunk), 4 slot-passes. Per pass:
// sim (gred16) -> online-softmax rescale of (vr,vi,d) -> update+LN+store (eff
// precomputed). After loop: flash-combine the 16 groups (global max, rescale,
// xor16/32 + 4 LDS rows), then z = g + v/D, complex LN, zf. 2 barriers before
// the loop, none inside. Mem traffic: 1 read + 1 write (write dead on last it).
__global__ __launch_bounds__(256) void k_main(
    const float* __restrict__ g_r, const float* __restrict__ g_i,
    const float* mem_r_src, const float* mem_i_src,   // may alias dst
    float* mem_r_dst, float* mem_i_dst,
    const float* __restrict__ effw,
    const float* __restrict__ lnr_w, const float* __restrict__ lnr_b,
    const float* __restrict__ lni_w, const float* __restrict__ lni_b,
    const float* __restrict__ cln_s, const float* __restrict__ cln_sh,
    float* __restrict__ zf, const int write_mem)
{
  const int t = threadIdx.x, b = blockIdx.x;
  const int lane = t & 63, w = t >> 6, sg = t >> 4, c = t & 15, d0 = c << 4;

  __shared__ float s_gr[320], s_gi[320];   // stride 20, elem d at (d>>4)*20+(d&15)
  __shared__ float s_eff[NS];
  __shared__ float s_redA[4*288], s_redB[4*288];  // 4 rows, chunk stride 18
  __shared__ float s_md[8];                // [0..3] wave maxes, [4..7] wave denoms
  __shared__ float s_pq[8];                // cLN mean/sumsq partials

  // phase 0: g -> LDS, eff -> LDS
  {
    float gr = g_r[(size_t)b*ND + t];
    float gi = g_i[(size_t)b*ND + t];
    s_gr[(t>>4)*20 + c] = gr;
    s_gi[(t>>4)*20 + c] = gi;
  }
  if (t < NS) s_eff[t] = effw[(size_t)b*NS + t];
  __syncthreads();                         // A

  float gr_[16], gi_[16];
  {
    const float4* p4r = reinterpret_cast<const float4*>(&s_gr[c*20]);
    const float4* p4i = reinterpret_cast<const float4*>(&s_gi[c*20]);
#pragma unroll
    for (int q = 0; q < 4; q++){
      float4 a4 = p4r[q], b4 = p4i[q];
      gr_[4*q+0]=a4.x; gr_[4*q+1]=a4.y; gr_[4*q+2]=a4.z; gr_[4*q+3]=a4.w;
      gi_[4*q+0]=b4.x; gi_[4*q+1]=b4.y; gi_[4*q+2]=b4.z; gi_[4*q+3]=b4.w;
    }
  }

  float vr[16], vi[16];
#pragma unroll
  for (int j = 0; j < 16; j++){ vr[j] = 0.f; vi[j] = 0.f; }
  float m_loc = -3.4e38f, d_loc = 0.f;

#pragma unroll 1
  for (int p = 0; p < 4; p++){
    const int sl = (p << 4) + sg;
    const size_t mbase = ((size_t)b*NS + sl)*ND + d0;
    float mr[16], mi[16];
    {
      const float4* pr = reinterpret_cast<const float4*>(mem_r_src + mbase);
      const float4* pi = reinterpret_cast<const float4*>(mem_i_src + mbase);
#pragma unroll
      for (int q = 0; q < 4; q++){
        float4 va = pr[q], vb = pi[q];
        mr[4*q+0]=va.x; mr[4*q+1]=va.y; mr[4*q+2]=va.z; mr[4*q+3]=va.w;
        mi[4*q+0]=vb.x; mi[4*q+1]=vb.y; mi[4*q+2]=vb.z; mi[4*q+3]=vb.w;
      }
    }
    // sim for this slot (group-uniform after gred)
    float sp = 0.f;
#pragma unroll
    for (int j = 0; j < 16; j++) sp += mr[j]*gr_[j] + mi[j]*gi_[j];
    sp = gred_sum16(sp);
    // online softmax accumulate (branch uniform per 16-lane group)
    if (sp > m_loc){
      float scv = expf(m_loc - sp);   // first pass: exp(-huge)=0
      d_loc *= scv;
#pragma unroll
      for (int j = 0; j < 16; j++){ vr[j] *= scv; vi[j] *= scv; }
      m_loc = sp;
    }
    {
      float w_ = expf(sp - m_loc);
      d_loc += w_;
#pragma unroll
      for (int j = 0; j < 16; j++){ vr[j] += w_*mr[j]; vi[j] += w_*mi[j]; }
    }
    // memory update + per-slot LayerNorm + store (dead on final iteration)
    if (write_mem){
      const float effv = s_eff[sl];
      const float onem = 1.f - effv;
      // real
      {
        float ps = 0.f;
#pragma unroll
        for (int j = 0; j < 16; j++){ mr[j] = onem*mr[j] + effv*gr_[j]; ps += mr[j]; }
        float mu = gred_sum16(ps) * (1.f/ND);
        float vs = 0.f;
#pragma unroll
        for (int j = 0; j < 16; j++){ float d_ = mr[j]-mu; vs += d_*d_; }
        float var = gred_sum16(vs) * (1.f/ND);
        float inv = 1.f / sqrtf(var + 1e-6f);
        const float4* lw4 = reinterpret_cast<const float4*>(lnr_w + d0);
        const float4* lb4 = reinterpret_cast<const float4*>(lnr_b + d0);
        float4* pd = reinterpret_cast<float4*>(mem_r_dst + mbase);
#pragma unroll
        for (int q = 0; q < 4; q++){
          float4 wv = lw4[q], bv = lb4[q];
          pd[q] = make_float4((mr[4*q+0]-mu)*inv*wv.x + bv.x,
                              (mr[4*q+1]-mu)*inv*wv.y + bv.y,
                              (mr[4*q+2]-mu)*inv*wv.z + bv.z,
                              (mr[4*q+3]-mu)*inv*wv.w + bv.w);
        }
      }
      // imag
      {
        float ps = 0.f;
#pragma unroll
        for (int j = 0; j < 16; j++){ mi[j] = onem*mi[j] + effv*gi_[j]; ps += mi[j]; }
        float mu = gred_sum16(ps) * (1.f/ND);
        float vs = 0.f;
#pragma unroll
        for (int j = 0; j < 16; j++){ float d_ = mi[j]-mu; vs += d_*d_; }
        float var = gred_sum16(vs) * (1.f/ND);
        float inv = 1.f / sqrtf(var + 1e-6f);
        const float4* lw4 = reinterpret_cast<const float4*>(lni_w + d0);
        const float4* lb4 = reinterpret_cast<const float4*>(lni_b + d0);
        float4* pd = reinterpret_cast<float4*>(mem_i_dst + mbase);
#pragma unroll
        for (int q = 0; q < 4; q++){
          float4 wv = lw4[q], bv = lb4[q];
          pd[q] = make_float4((mi[4*q+0]-mu)*inv*wv.x + bv.x,
                              (mi[4*q+1]-mu)*inv*wv.y + bv.y,
                              (mi[4*q+2]-mu)*inv*wv.z + bv.z,
                              (mi[4*q+3]-mu)*inv*wv.w + bv.w);
        }
      }
    }
  }

  // ---- flash combine across the 16 slot-groups ----
  {
    float mm = wred_max64(m_loc);
    if (lane == 0) s_md[w] = mm;
  }
  __syncthreads();                         // B
  const float M = fmaxf(fmaxf(s_md[0], s_md[1]), fmaxf(s_md[2], s_md[3]));
  const float scl = expf(m_loc - M);
  {
    float dd = (c == 0) ? d_loc * scl : 0.f;
    dd = wred_sum64(dd);
    if (lane == 0) s_md[4+w] = dd;
  }
  {
    const bool wr_ok = (lane < 16);
#pragma unroll
    for (int j = 0; j < 16; j += 2){
      float y0 = vr[j]*scl, y1 = vr[j+1]*scl;
      y0 += __shfl_xor(y0, 16, 64); y0 += __shfl_xor(y0, 32, 64);
      y1 += __shfl_xor(y1, 16, 64); y1 += __shfl_xor(y1, 32, 64);
      float z0 = vi[j]*scl, z1 = vi[j+1]*scl;
      z0 += __shfl_xor(z0, 16, 64); z0 += __shfl_xor(z0, 32, 64);
      z1 += __shfl_xor(z1, 16, 64); z1 += __shfl_xor(z1, 32, 64);
      if (wr_ok){
        *reinterpret_cast<float2*>(&s_redA[w*288 + lane*18 + j]) = make_float2(y0, y1);
        *reinterpret_cast<float2*>(&s_redB[w*288 + lane*18 + j]) = make_float2(z0, z1);
      }
    }
  }
  __syncthreads();                         // C
  const float D = s_md[4] + s_md[5] + s_md[6] + s_md[7];

  // ---- gather read, z = g + read, complex layernorm ----
  {
    const int offp = (t >> 4)*18 + c;
    float rr = 0.f, ri = 0.f;
#pragma unroll
    for (int w2 = 0; w2 < 4; w2++){
      rr += s_redA[w2*288 + offp];
      ri += s_redB[w2*288 + offp];
    }
    const float invD = 1.f / D;
    rr *= invD; ri *= invD;
    const int offg = (t >> 4)*20 + c;
    float zr = s_gr[offg] + rr;
    float zi = s_gi[offg] + ri;
    float mag = sqrtf(zr*zr + zi*zi + 1e-8f);
    float s1 = wred_sum64(mag);
    float s2 = wred_sum64(mag*mag);
    if (lane == 0){ s_pq[w] = s1; s_pq[4+w] = s2; }
    __syncthreads();                       // D
    const float meanv = (s_pq[0]+s_pq[1]+s_pq[2]+s_pq[3]) * (1.f/ND);
    const float sumsq = s_pq[4]+s_pq[5]+s_pq[6]+s_pq[7];
    const float varv  = (sumsq - (float)ND*meanv*meanv) * (1.f/(ND-1));  // ddof=1
    float nm = (mag - meanv) / sqrtf(varv + 1e-4f) * cln_s[t] + cln_sh[t];
    float sc = nm / mag;
    zf[(size_t)b*(2*ND) + t]      = sc * zr;
    zf[(size_t)b*(2*ND) + ND + t] = sc * zi;
  }
}

// ---------------- K2: batched VQ distances + per-tile argmin -----------------
__global__ __launch_bounds__(256) void k_vq_dist(
    const float* __restrict__ zf, const float* __restrict__ codebook,
    const float* __restrict__ ysq, float* __restrict__ pvals, int* __restrict__ pidx)
{
  const int t = threadIdx.x;
  const int mt = blockIdx.x >> 2, nt = blockIdx.x & 3;
  const int sb = mt*32, cbase = nt*256;
  const int jg = t & 31;
  const int ig = t >> 5;

  __shared__ float s_a[16*36];
  __shared__ float s_b[16*260];

  float accv[4][8];
#pragma unroll
  for (int i = 0; i < 4; i++)
#pragma unroll
    for (int j = 0; j < 8; j++) accv[i][j] = 0.f;

  for (int k0 = 0; k0 < 2*ND; k0 += 16){
#pragma unroll
    for (int p = 0; p < 2; p++){
      int e = t + p*256; int i_ = e >> 4; int k_ = e & 15;
      s_a[k_*36 + i_] = zf[(size_t)(sb+i_)*(2*ND) + k0 + k_];
    }
#pragma unroll
    for (int p = 0; p < 16; p++){
      int e = t + p*256; int c_ = e >> 4; int k_ = e & 15;
      s_b[k_*260 + c_] = codebook[(size_t)(cbase+c_)*(2*ND) + k0 + k_];
    }
    __syncthreads();
#pragma unroll
    for (int k = 0; k < 16; k++){
      float4 a4 = *reinterpret_cast<const float4*>(&s_a[k*36 + ig*4]);
      float4 b0 = *reinterpret_cast<const float4*>(&s_b[k*260 + jg*8]);
      float4 b1 = *reinterpret_cast<const float4*>(&s_b[k*260 + jg*8 + 4]);
      const float av[4] = {a4.x, a4.y, a4.z, a4.w};
      const float bv[8] = {b0.x,b0.y,b0.z,b0.w,b1.x,b1.y,b1.z,b1.w};
#pragma unroll
      for (int i = 0; i < 4; i++)
#pragma unroll
        for (int j = 0; j < 8; j++) accv[i][j] = fmaf(av[i], bv[j], accv[i][j]);
    }
    __syncthreads();
  }

#pragma unroll
  for (int i = 0; i < 4; i++){
    float bvv = 1e30f; int bii = 0;
#pragma unroll
    for (int j = 0; j < 8; j++){
      int cg = cbase + jg*8 + j;
      float sc = ysq[cg] - 2.f*accv[i][j];
      if (sc < bvv){ bvv = sc; bii = cg; }
    }
#pragma unroll
    for (int m = 1; m < 32; m <<= 1){
      float ov = __shfl_xor(bvv, m, 64); int oi = __shfl_xor(bii, m, 64);
      if (ov < bvv || (ov == bvv && oi < bii)){ bvv = ov; bii = oi; }
    }
    if (jg == 0){
      int smp = sb + ig*4 + i;
      pvals[smp*4 + nt] = bvv;
      pidx [smp*4 + nt] = bii;
    }
  }
}

// ---------------- K3: combine argmin, hist, loss, write next g / output ------
__global__ __launch_bounds__(64) void k_vq_pick(
    const float* __restrict__ pvals, const int* __restrict__ pidx,
    const float* __restrict__ codebook, const float* zf,
    float* __restrict__ g_r, float* __restrict__ g_i, float* out,
    const int final_it, int* __restrict__ hist, float* __restrict__ dsv)
{
  const int b = blockIdx.x, lanev = threadIdx.x;
  int sidx = 0;
  if (lanev == 0){
    float bv = pvals[b*4]; int bi = pidx[b*4];
#pragma unroll
    for (int nt = 1; nt < 4; nt++){
      float v = pvals[b*4+nt]; int id = pidx[b*4+nt];
      if (v < bv || (v == bv && id < bi)){ bv = v; bi = id; }
    }
    sidx = bi;
    atomicAdd(&hist[sidx], 1);   // scattered: low contention
  }
  sidx = __shfl(sidx, 0, 64);

  const int e0 = lanev*8;
  const float4* cp = reinterpret_cast<const float4*>(codebook + (size_t)sidx*(2*ND) + e0);
  float4 c0 = cp[0], c1 = cp[1];
  const float4* zp = reinterpret_cast<const float4*>(zf + (size_t)b*(2*ND) + e0);
  float4 z0 = zp[0], z1 = zp[1];
  float ds_ = (c0.x-z0.x)*(c0.x-z0.x) + (c0.y-z0.y)*(c0.y-z0.y)
            + (c0.z-z0.z)*(c0.z-z0.z) + (c0.w-z0.w)*(c0.w-z0.w)
            + (c1.x-z1.x)*(c1.x-z1.x) + (c1.y-z1.y)*(c1.y-z1.y)
            + (c1.z-z1.z)*(c1.z-z1.z) + (c1.w-z1.w)*(c1.w-z1.w);
  ds_ = wred_sum64(ds_);
  if (lanev == 0) dsv[b] = ds_;   // plain store; summed in k_final

  if (final_it){
    float4* op = reinterpret_cast<float4*>(out + (size_t)b*(2*ND) + e0);
    op[0] = c0; op[1] = c1;
  } else if (e0 < ND){
    float4* gp = reinterpret_cast<float4*>(g_r + (size_t)b*ND + e0);
    gp[0] = c0; gp[1] = c1;
  } else {
    float4* gp = reinterpret_cast<float4*>(g_i + (size_t)b*ND + (e0-ND));
    gp[0] = c0; gp[1] = c1;
  }
}

// ---------------- K4: aux = slot_ent + vq_loss + codebook entropies ----------
__global__ __launch_bounds__(256) void k_final(const int* __restrict__ hist,
                                               const float* __restrict__ ent,
                                               const float* __restrict__ dsv,
                                               float* __restrict__ out)
{
  __shared__ float redh[256], reda[256];
  const int t = threadIdx.x;
  float h = 0.f;
  for (int it = 0; it < NREC; it++){
    for (int k = t; k < NK; k += 256){
      float p = (float)hist[it*NK + k] * (1.f/NB);
      h += p * logf(p + 1e-10f);
    }
  }
  float a = 0.f;
  for (int i = t; i < NREC*NB; i += 256) a += ent[i];
  float d = 0.f;
  for (int i = t; i < NREC*NB; i += 256) d += dsv[i];
  redh[t] = h;
  reda[t] = a * (1.f/NB) + d * (BETA/(2.f*ND*NB));
  __syncthreads();
  for (int off = 128; off > 0; off >>= 1){
    if (t < off){ redh[t] += redh[t+off]; reda[t] += reda[t+off]; }
    __syncthreads();
  }
  if (t == 0) out[(size_t)NB*2*ND] = reda[0] - redh[0] * (1.f/logf((float)NK));
}

// ---------------- host launch ----------------
extern "C" void kernel_launch(void* const* d_in, const int* in_sizes, int n_in,
                              void* d_out, int out_size, void* d_ws, size_t ws_size,
                              hipStream_t stream)
{
  const float* gwr    = (const float*)d_in[0];
  const float* gwi    = (const float*)d_in[1];
  float*       memr_in= (float*)d_in[2];
  float*       memi_in= (float*)d_in[3];
  const float* gate_w = (const float*)d_in[4];
  const float* gate_b = (const float*)d_in[5];
  const float* addr_w = (const float*)d_in[6];
  const float* addr_b = (const float*)d_in[7];
  const float* lnr_w  = (const float*)d_in[8];
  const float* lnr_b  = (const float*)d_in[9];
  const float* lni_w  = (const float*)d_in[10];
  const float* lni_b  = (const float*)d_in[11];
  const float* cln_s  = (const float*)d_in[12];
  const float* cln_sh = (const float*)d_in[13];
  const float* codebook = (const float*)d_in[14];
  float* out = (float*)d_out;
  char* wsb = (char*)d_ws;

  // ws layout (bytes)
  const size_t OFF_HIST = 256;        // 5*1024 ints   -> 20736
  const size_t OFF_ENT  = 20736;      // 5*2048 f      -> 61696
  const size_t OFF_DS   = 61696;      // 5*2048 f      -> 102656
  const size_t OFF_YSQ  = 102656;     // 1024 f        -> 106752
  const size_t OFF_PV   = 106752;     // 2048*4 f      -> 139520
  const size_t OFF_PI   = 139520;     // 2048*4 i      -> 172288
  const size_t OFF_EFF  = 172288;     // 2048*64 f     -> 696576
  const size_t OFF_GR   = 696576;     // 2048*256 f    -> 2793728
  const size_t OFF_GI   = 2793728;    //               -> 4890880
  const size_t OFF_ZF   = 4890880;    // 2048*512 f    -> 9085184
  const size_t OFF_MR   = 9085184;    // 2048*64*256 f -> 143302912
  const size_t OFF_MI   = 143302912;  //               -> 277520640
  const size_t NEED_BIG = 277520640;
  const size_t NEED_MID = 9085184;
  const size_t NEED_TINY = 696576;

  if (ws_size < NEED_TINY) return;   // cannot run safely

  int*   hist  = (int*)  (wsb + OFF_HIST);
  float* ws_ent= (float*)(wsb + OFF_ENT);
  float* ws_ds = (float*)(wsb + OFF_DS);
  float* ysq   = (float*)(wsb + OFF_YSQ);
  float* pvals = (float*)(wsb + OFF_PV);
  int*   pidx  = (int*)  (wsb + OFF_PI);
  float* effw  = (float*)(wsb + OFF_EFF);

  const bool big = ws_size >= NEED_BIG;
  const bool mid = ws_size >= NEED_MID;

  float* memr_buf = big ? (float*)(wsb + OFF_MR) : memr_in;
  float* memi_buf = big ? (float*)(wsb + OFF_MI) : memi_in;
  float* g_rp = mid ? (float*)(wsb + OFF_GR) : (float*)d_in[0];
  float* g_ip = mid ? (float*)(wsb + OFF_GI) : (float*)d_in[1];
  float* zfp  = mid ? (float*)(wsb + OFF_ZF) : out;

  (void)hipMemsetAsync(wsb, 0, OFF_YSQ, stream);   // hist + ent + ds

  k_ysq<<<dim3(NK), dim3(64), 0, stream>>>(codebook, ysq);

  const float* gsr = gwr; const float* gsi = gwi;
  const float* msr = memr_in; const float* msi = memi_in;
  for (int it = 0; it < NREC; it++){
    const int write_mem = (it == NREC-1) ? 0 : 1;
    k_eff<<<dim3(NB), dim3(256), 0, stream>>>(
        gsr, gsi, addr_w, addr_b, gate_w, gate_b,
        effw, ws_ent + (size_t)it*NB);
    k_main<<<dim3(NB), dim3(256), 0, stream>>>(
        gsr, gsi, msr, msi, memr_buf, memi_buf, effw,
        lnr_w, lnr_b, lni_w, lni_b, cln_s, cln_sh, zfp, write_mem);
    k_vq_dist<<<dim3(256), dim3(256), 0, stream>>>(zfp, codebook, ysq, pvals, pidx);
    k_vq_pick<<<dim3(NB), dim3(64), 0, stream>>>(
        pvals, pidx, codebook, zfp, g_rp, g_ip, out,
        (it == NREC-1) ? 1 : 0, hist + it*NK, ws_ds + (size_t)it*NB);
    gsr = g_rp; gsi = g_ip;
    msr = memr_buf; msi = memi_buf;
  }
  k_final<<<dim3(1), dim3(256), 0, stream>>>(hist, ws_ent, ws_ds, out);
}